// Round 8
// baseline (368.170 us; speedup 1.0000x reference)
//
#include <hip/hip_runtime.h>

#define DIMN 4096
#define DIMB 4
#define DIMH 16
#define DIMK 64
#define DH   64

typedef __attribute__((ext_vector_type(8))) __bf16 bf16x8;
typedef __attribute__((ext_vector_type(8))) _Float16 f16x8;
typedef __attribute__((ext_vector_type(8))) unsigned short u16x8;
typedef __attribute__((ext_vector_type(4))) float f32x4;
typedef __attribute__((ext_vector_type(4))) int i32x4;

__device__ __forceinline__ unsigned short f2bf(float f) {
  union { float f; unsigned u; } v; v.f = f;
  unsigned r = v.u + 0x7FFFu + ((v.u >> 16) & 1u);
  return (unsigned short)(r >> 16);
}
__device__ __forceinline__ float bf2f(unsigned short u) {
  union { unsigned u; float f; } v; v.u = ((unsigned)u) << 16; return v.f;
}
// split f32 -> (hi, lo) bf16 pair: hi+lo ~ f with ~2^-17 rel error
__device__ __forceinline__ void split2(float f, unsigned short& h, unsigned short& l) {
  h = f2bf(f);
  l = f2bf(f - bf2f(h));
}
__device__ __forceinline__ unsigned short f2h(float f) {
  _Float16 h = (_Float16)f;
  return __builtin_bit_cast(unsigned short, h);
}
__device__ __forceinline__ bf16x8 ldbf8(const unsigned short* p) {
  return __builtin_bit_cast(bf16x8, *(const u16x8*)p);
}
__device__ __forceinline__ f16x8 ldh8(const unsigned short* p) {
  return __builtin_bit_cast(f16x8, *(const u16x8*)p);
}
__device__ __forceinline__ f32x4 mfma16(bf16x8 a, bf16x8 b, f32x4 c) {
  return __builtin_amdgcn_mfma_f32_16x16x32_bf16(a, b, c, 0, 0, 0);
}
__device__ __forceinline__ f32x4 mfma16h(f16x8 a, f16x8 b, f32x4 c) {
  return __builtin_amdgcn_mfma_f32_16x16x32_f16(a, b, c, 0, 0, 0);
}

// ---- global->LDS direct DMA, 16B per lane; LDS dest is wave-uniform base + lane*16 ----
__device__ __forceinline__ void gl_lds16(const unsigned short* g, unsigned short* l) {
  __builtin_amdgcn_global_load_lds(
      (const __attribute__((address_space(1))) unsigned int*)g,
      (__attribute__((address_space(3))) unsigned int*)l, 16, 0, 0);
}

// Stage a [128][32]-ushort tile (linear LDS, 64B rows) from row-major src (stride elems).
// XOR-swizzled source slot f(row)=(row>>1)&3: LDS[row][slot] holds global slot (slot^f).
// 16B-unit = (row&1)*4 + quad^f(row): 16 consecutive rows cover all 8 units twice -> 2-way (free).
// Reads must use frag_ptr below (same involution). [guide §5 rule 21, §6 G4]
__device__ __forceinline__ void stage_tile(const unsigned short* src, int stride,
                                           unsigned short* lds, int tid, int k0) {
  const int wave = tid >> 6;
  #pragma unroll
  for (int s = 0; s < 2; ++s) {
    int idx = tid + s * 256;
    int row = idx >> 2;
    int slot = idx & 3;
    gl_lds16(&src[(size_t)row * stride + k0 + ((slot ^ ((row >> 1) & 3)) * 8)],
             &lds[(size_t)(s * 256 + wave * 64) * 8]);
  }
}
__device__ __forceinline__ const unsigned short* frag_ptr(const unsigned short* lds,
                                                          int row, int quad) {
  return &lds[row * 32 + ((quad ^ ((row >> 1) & 3)) * 8)];
}

// ------------- transpose + cast: src (R,C) f32 -> dst (C,R) bf16 [PROVEN r3] -------------
__global__ void transpose_cast(const float* __restrict__ src, unsigned short* __restrict__ dst,
                               int R, int C) {
  __shared__ float tile[32][33];
  int c0 = blockIdx.x * 32, r0 = blockIdx.y * 32;
  for (int i = threadIdx.y; i < 32; i += 8)
    tile[i][threadIdx.x] = src[(size_t)(r0 + i) * C + c0 + threadIdx.x];
  __syncthreads();
  for (int i = threadIdx.y; i < 32; i += 8)
    dst[(size_t)(c0 + i) * R + r0 + threadIdx.x] = f2bf(tile[threadIdx.x][i]);
}

// ------------- transpose + cast fp16 of Wqkv[:, :1024] -> WqT (1024x1024, [n][k]) -------------
__global__ void transpose_wq_f16(const float* __restrict__ W, unsigned short* __restrict__ t) {
  __shared__ float tile[32][33];
  int c0 = blockIdx.x * 32, r0 = blockIdx.y * 32;   // c: n (col of Wq), r: k (row of Wq)
  for (int i = threadIdx.y; i < 32; i += 8)
    tile[i][threadIdx.x] = W[(size_t)(r0 + i) * 3072 + c0 + threadIdx.x];
  __syncthreads();
  for (int i = threadIdx.y; i < 32; i += 8)
    t[(size_t)(c0 + i) * 1024 + r0 + threadIdx.x] = f2h(tile[threadIdx.x][i]);
}

// ------------- transpose + hi/lo split of Wqkv[:, 1024:3072] -> WkvT (2048 x 1024, [n][k]) -------------
__global__ void transpose_split_wkv(const float* __restrict__ W,
                                    unsigned short* __restrict__ th,
                                    unsigned short* __restrict__ tl) {
  __shared__ float tile[32][33];
  int c0 = blockIdx.x * 32, r0 = blockIdx.y * 32;   // c: 0..2047 (col-1024), r: k
  for (int i = threadIdx.y; i < 32; i += 8)
    tile[i][threadIdx.x] = W[(size_t)(r0 + i) * 3072 + 1024 + c0 + threadIdx.x];
  __syncthreads();
  for (int i = threadIdx.y; i < 32; i += 8) {
    float v = tile[threadIdx.x][i];
    unsigned short h, l; split2(v, h, l);
    size_t o = (size_t)(c0 + i) * 1024 + r0 + threadIdx.x;
    th[o] = h;
    tl[o] = l;
  }
}

// ------------- transpose + cast fp16 of E,F (4096x64) -> EFt (128 kk x 4096 n) -------------
__global__ void transpose_EF_f16(const float* __restrict__ E, const float* __restrict__ F,
                                 unsigned short* __restrict__ t) {
  __shared__ float tile[32][33];
  const float* src = blockIdx.z ? F : E;
  const int kkbase = blockIdx.z * 64;
  int c0 = blockIdx.x * 32, r0 = blockIdx.y * 32;   // c: k-col of E, r: n
  for (int i = threadIdx.y; i < 32; i += 8)
    tile[i][threadIdx.x] = src[(size_t)(r0 + i) * 64 + c0 + threadIdx.x];
  __syncthreads();
  for (int i = threadIdx.y; i < 32; i += 8)
    t[(size_t)(kkbase + c0 + i) * 4096 + r0 + threadIdx.x] = f2h(tile[threadIdx.x][i]);
}

// ------------- cast x (16M f32) -> fp16 (memory-bound, vectorized) -------------
__global__ __launch_bounds__(256) void cast_x_f16(
    const float* __restrict__ src, unsigned short* __restrict__ d) {
  const int total4 = DIMN * DIMB * 1024 / 4;   // 4,194,304 float4s
  int i = blockIdx.x * 256 + threadIdx.x;
  const int stride = gridDim.x * 256;
  for (; i < total4; i += stride) {
    float4 v = ((const float4*)src)[i];
    ushort4 h;
    h.x = f2h(v.x); h.y = f2h(v.y); h.z = f2h(v.z); h.w = f2h(v.w);
    ((ushort4*)d)[i] = h;
  }
}

// ------------- fp16 MFMA GEMM for q (DMA staging, dbuf prefetch, swizzled LDS) -------------
// q(16384x1024) = x @ Wq + bq ; scatter q (b,h,n,d) bf16. A=[m][k] fp16, Bt=[n][k] fp16.
__global__ __launch_bounds__(256) void gemm_q_f16(
    const unsigned short* __restrict__ A, const unsigned short* __restrict__ Bt,
    const float* __restrict__ bias, unsigned short* __restrict__ q)
{
  __shared__ unsigned short As0[128 * 32], As1[128 * 32];
  __shared__ unsigned short Bs0[128 * 32], Bs1[128 * 32];
  const int tid  = threadIdx.x;
  const int wave = tid >> 6, lane = tid & 63;
  const int quad = lane >> 4, l16 = lane & 15;
  const int wm = (wave >> 1) * 64, wn = (wave & 1) * 64;
  const int m0 = blockIdx.x * 128, n0 = blockIdx.y * 128;
  const unsigned short* Ab = A  + (size_t)m0 * 1024;
  const unsigned short* Bb = Bt + (size_t)n0 * 1024;

  f32x4 acc[4][4] = {};

  stage_tile(Ab, 1024, As0, tid, 0);
  stage_tile(Bb, 1024, Bs0, tid, 0);
  __syncthreads();
  int cur = 0;
  for (int t = 0; t < 32; ++t) {
    const unsigned short* Ac = cur ? As1 : As0;
    const unsigned short* Bc = cur ? Bs1 : Bs0;
    unsigned short* An = cur ? As0 : As1;
    unsigned short* Bn = cur ? Bs0 : Bs1;
    f16x8 af[4], bfr[4];
    #pragma unroll
    for (int i = 0; i < 4; ++i) af[i]  = ldh8(frag_ptr(Ac, wm + 16 * i + l16, quad));
    #pragma unroll
    for (int j = 0; j < 4; ++j) bfr[j] = ldh8(frag_ptr(Bc, wn + 16 * j + l16, quad));
    if (t < 31) {                            // prefetch next K-tile into other buffer
      stage_tile(Ab, 1024, An, tid, (t + 1) * 32);
      stage_tile(Bb, 1024, Bn, tid, (t + 1) * 32);
    }
    #pragma unroll
    for (int i = 0; i < 4; ++i)
      #pragma unroll
      for (int j = 0; j < 4; ++j)
        acc[i][j] = mfma16h(af[i], bfr[j], acc[i][j]);
    if (t < 31) __syncthreads();             // drains prefetch (hidden under MFMA) + read-safety
    cur ^= 1;
  }

  #pragma unroll
  for (int i = 0; i < 4; ++i)
    #pragma unroll
    for (int j = 0; j < 4; ++j) {
      int col = n0 + wn + 16 * j + l16;     // 0..1023 (q cols)
      float bs = bias[col];
      int h = col >> 6, d = col & 63;
      #pragma unroll
      for (int r = 0; r < 4; ++r) {
        int row = m0 + wm + 16 * i + quad * 4 + r;
        int n = row >> 2, b = row & 3;      // x row-major (N,B,DIM): row = n*4+b
        q[(((size_t)(b * DIMH + h) * DIMN + n) << 6) + d] = f2bf(acc[i][j][r] + bs);
      }
    }
}

// ------------- split-K fp16 MFMA GEMM: partial[ks][kk128][c4096] = EFt[kk][n] . x[n][c] -------------
__global__ __launch_bounds__(256) void gemm_xEF(
    const unsigned short* __restrict__ xf, const unsigned short* __restrict__ ef,
    float* __restrict__ partial)
{
  __shared__ unsigned short Ash[128 * 40];
  __shared__ unsigned short Bsh[128 * 40];
  const int tid  = threadIdx.x;
  const int wave = tid >> 6, lane = tid & 63;
  const int quad = lane >> 4, l16 = lane & 15;
  const int wm = (wave >> 1) * 64, wn = (wave & 1) * 64;
  const int c0 = blockIdx.x * 128;
  const int ks = blockIdx.y;

  f32x4 acc[4][4] = {};

  const int kend = ks * 512 + 512;
  for (int k0 = ks * 512; k0 < kend; k0 += 32) {
    #pragma unroll
    for (int s = 0; s < 2; ++s) {
      int idx = tid + s * 256;
      int row = idx >> 2;             // kk 0..127
      int kc  = (idx & 3) * 8;        // n-local 0..31
      *(i32x4*)&Ash[row * 40 + kc] = *(const i32x4*)&ef[(size_t)row * 4096 + k0 + kc];
    }
    // B staging: LDS transpose-scatter x[n][c] -> Bs[c][n]
    #pragma unroll
    for (int s = 0; s < 2; ++s) {
      int n_l = tid & 31;
      int c8  = (tid >> 5) + s * 8;   // 0..15
      u16x8 vh = *(const u16x8*)&xf[(size_t)(k0 + n_l) * 4096 + c0 + c8 * 8];
      #pragma unroll
      for (int e = 0; e < 8; ++e)
        Bsh[(c8 * 8 + e) * 40 + n_l] = vh[e];
    }
    __syncthreads();
    f16x8 afh[4], bfh[4];
    #pragma unroll
    for (int i = 0; i < 4; ++i) afh[i] = ldh8(&Ash[(wm + 16 * i + l16) * 40 + quad * 8]);
    #pragma unroll
    for (int j = 0; j < 4; ++j) bfh[j] = ldh8(&Bsh[(wn + 16 * j + l16) * 40 + quad * 8]);
    #pragma unroll
    for (int i = 0; i < 4; ++i)
      #pragma unroll
      for (int j = 0; j < 4; ++j)
        acc[i][j] = mfma16h(afh[i], bfh[j], acc[i][j]);
    __syncthreads();
  }

  #pragma unroll
  for (int i = 0; i < 4; ++i)
    #pragma unroll
    for (int j = 0; j < 4; ++j) {
      int col = c0 + wn + 16 * j + l16;
      #pragma unroll
      for (int r = 0; r < 4; ++r) {
        int m = wm + 16 * i + quad * 4 + r;   // kk' 0..127
        partial[((size_t)ks * 128 + m) * 4096 + col] = acc[i][j][r];
      }
    }
}

// ------------- reduce split-K partials -> xEF bf16 hi/lo in [m][k] GEMM layout -------------
// m = t*256 + b*64 + (kk&63), k = c&1023  (t = kk>>6, b = c>>10)
__global__ __launch_bounds__(256) void reduce_xEF2(
    const float* __restrict__ partial, unsigned short* __restrict__ xh,
    unsigned short* __restrict__ xl)
{
  int t_lin = blockIdx.x * 256 + threadIdx.x;   // kk*4096 + c
  float s = 0.f;
  #pragma unroll
  for (int ks = 0; ks < 8; ++ks)
    s += partial[(size_t)ks * 524288 + t_lin];
  int kk = t_lin >> 12, c = t_lin & 4095;
  int t = kk >> 6, kkl = kk & 63, b = c >> 10, k = c & 1023;
  int m = t * 256 + b * 64 + kkl;
  unsigned short h, l; split2(s, h, l);
  xh[m * 1024 + k] = h;
  xl[m * 1024 + k] = l;
}

// ------------- column sums of E,F stage 1: partS[src][chunk16][kk64] -------------
__global__ __launch_bounds__(256) void colsum_EF1(
    const float* __restrict__ E, const float* __restrict__ F,
    float* __restrict__ partS)
{
  const int src = blockIdx.x;          // 0..1
  const int ch  = blockIdx.y;          // 0..15
  const float* S = src ? F : E;
  const int r  = threadIdx.x >> 6;     // 0..3
  const int kk = threadIdx.x & 63;
  const int n0 = ch * 256;
  float s = 0.f;
  #pragma unroll 8
  for (int i = 0; i < 64; ++i)
    s += S[(size_t)(n0 + r + 4 * i) * 64 + kk];
  __shared__ float red[4][64];
  red[r][kk] = s;
  __syncthreads();
  if (r == 0)
    partS[((size_t)src * 16 + ch) * 64 + kk] = red[0][kk] + red[1][kk] + red[2][kk] + red[3][kk];
}

// ------------- column sums stage 2: sEF[src*64+kk] = sum_ch partS -------------
__global__ void colsum_EF2(const float* __restrict__ partS, float* __restrict__ sEF) {
  int t = threadIdx.x;                 // 0..127
  int src = t >> 6, kk = t & 63;
  float s = 0.f;
  #pragma unroll
  for (int ch = 0; ch < 16; ++ch)
    s += partS[((size_t)src * 16 + ch) * 64 + kk];
  sEF[t] = s;
}

// ------------- klow/vlow via 3-product bf16 MFMA GEMM (M=512, N=1024, K=1024) -------------
// A = xEF hi/lo [m][k] (m = t*256+b*64+kk); B = WkvT hi/lo [t*1024+c][k].
// global_load_lds staging + swizzled LDS. Epilogue adds sEF[kk]*bias, scatters fp32.
__global__ __launch_bounds__(256) void gemm_klv(
    const unsigned short* __restrict__ Ah, const unsigned short* __restrict__ Al,
    const unsigned short* __restrict__ Bh, const unsigned short* __restrict__ Bl,
    const float* __restrict__ bias, const float* __restrict__ sEF,
    float* __restrict__ klow, float* __restrict__ vlow)
{
  __shared__ unsigned short Ash[128 * 32], Asl[128 * 32];
  __shared__ unsigned short Bsh[128 * 32], Bsl[128 * 32];
  const int tid  = threadIdx.x;
  const int wave = tid >> 6, lane = tid & 63;
  const int quad = lane >> 4, l16 = lane & 15;
  const int wm = (wave >> 1) * 64, wn = (wave & 1) * 64;
  const int mt = blockIdx.y;           // 0..3
  const int t  = mt >> 1;
  const int m0 = mt * 128;
  const int n0 = blockIdx.x * 128;     // c-tile within t
  const int brow = t * 1024 + n0;
  const unsigned short* Ahb = Ah + (size_t)m0 * 1024;
  const unsigned short* Alb = Al + (size_t)m0 * 1024;
  const unsigned short* Bhb = Bh + (size_t)brow * 1024;
  const unsigned short* Blb = Bl + (size_t)brow * 1024;

  f32x4 acc[4][4] = {};

  for (int k0 = 0; k0 < 1024; k0 += 32) {
    stage_tile(Ahb, 1024, Ash, tid, k0);
    stage_tile(Alb, 1024, Asl, tid, k0);
    stage_tile(Bhb, 1024, Bsh, tid, k0);
    stage_tile(Blb, 1024, Bsl, tid, k0);
    __syncthreads();
    bf16x8 afh[4], afl[4], bfh[4], bfl[4];
    #pragma unroll
    for (int i = 0; i < 4; ++i) {
      afh[i] = ldbf8(frag_ptr(Ash, wm + 16 * i + l16, quad));
      afl[i] = ldbf8(frag_ptr(Asl, wm + 16 * i + l16, quad));
    }
    #pragma unroll
    for (int j = 0; j < 4; ++j) {
      bfh[j] = ldbf8(frag_ptr(Bsh, wn + 16 * j + l16, quad));
      bfl[j] = ldbf8(frag_ptr(Bsl, wn + 16 * j + l16, quad));
    }
    #pragma unroll
    for (int i = 0; i < 4; ++i)
      #pragma unroll
      for (int j = 0; j < 4; ++j) {
        acc[i][j] = mfma16(afh[i], bfh[j], acc[i][j]);
        acc[i][j] = mfma16(afh[i], bfl[j], acc[i][j]);
        acc[i][j] = mfma16(afl[i], bfh[j], acc[i][j]);
      }
    __syncthreads();
  }

  float* dstb = (t ? vlow : klow);
  #pragma unroll
  for (int i = 0; i < 4; ++i)
    #pragma unroll
    for (int j = 0; j < 4; ++j) {
      int c = n0 + wn + 16 * j + l16;       // 0..1023
      int h = c >> 6, d = c & 63;
      float bs = bias[1024 * (1 + t) + c];
      #pragma unroll
      for (int r = 0; r < 4; ++r) {
        int m = m0 + wm + 16 * i + quad * 4 + r;
        int b = (m >> 6) & 3, kk = m & 63;
        float val = acc[i][j][r] + sEF[t * 64 + kk] * bs;
        dstb[(((size_t)b * DIMH + h) * DIMK + kk) * DH + d] = val;
      }
    }
}

// ------------- fused dots -> softmax -> PV -------------
// KL/VL fp32; K and V split hi/lo bf16 for MFMA (near-fp32 logits & PV).
__global__ __launch_bounds__(256) void attn_fused(
    const unsigned short* __restrict__ qb, const float* __restrict__ klow,
    const float* __restrict__ vlow, unsigned short* __restrict__ ctx)
{
  __shared__ unsigned short VTh[64][72], VTl[64][72];  // [d][k], k<72
  __shared__ unsigned short Plds[4][32][72];
  const int bh = blockIdx.x, b = bh >> 4, h = bh & 15;
  const unsigned short* Q  = qb   + (size_t)bh * DIMN * DH;
  const float* KL = klow + (size_t)bh * DIMK * DH;
  const float* VL = vlow + (size_t)bh * DIMK * DH;
  const int tid = threadIdx.x, wave = tid >> 6, lane = tid & 63;
  const int quad = lane >> 4, l16 = lane & 15;

  #pragma unroll
  for (int it = 0; it < 2; ++it) {
    int idx = tid + it * 256;
    int kk = idx >> 3, d0 = (idx & 7) * 8;
    float4 f0 = *(const float4*)&VL[kk * DH + d0];
    float4 f1 = *(const float4*)&VL[kk * DH + d0 + 4];
    float vv[8] = {f0.x, f0.y, f0.z, f0.w, f1.x, f1.y, f1.z, f1.w};
    #pragma unroll
    for (int e = 0; e < 8; ++e) {
      unsigned short hh, ll;
      split2(vv[e], hh, ll);
      VTh[d0 + e][kk] = hh;
      VTl[d0 + e][kk] = ll;
    }
  }
  bf16x8 kfh[2][4], kfl[2][4];
  #pragma unroll
  for (int dc = 0; dc < 2; ++dc)
    #pragma unroll
    for (int j = 0; j < 4; ++j) {
      const float* p = &KL[(j * 16 + l16) * DH + dc * 32 + quad * 8];
      float4 f0 = *(const float4*)p;
      float4 f1 = *(const float4*)(p + 4);
      float vv[8] = {f0.x, f0.y, f0.z, f0.w, f1.x, f1.y, f1.z, f1.w};
      alignas(16) unsigned short th[8], tl[8];
      #pragma unroll
      for (int e = 0; e < 8; ++e) split2(vv[e], th[e], tl[e]);
      kfh[dc][j] = ldbf8(th);
      kfl[dc][j] = ldbf8(tl);
    }
  __syncthreads();

  const int n_base = blockIdx.y * 128 + wave * 32;

  f32x4 sacc[2][4] = {};
  #pragma unroll
  for (int rt = 0; rt < 2; ++rt)
    #pragma unroll
    for (int dc = 0; dc < 2; ++dc) {
      bf16x8 a = ldbf8(&Q[(size_t)(n_base + rt * 16 + l16) * DH + dc * 32 + quad * 8]);
      #pragma unroll
      for (int j = 0; j < 4; ++j) {
        sacc[rt][j] = mfma16(a, kfh[dc][j], sacc[rt][j]);
        sacc[rt][j] = mfma16(a, kfl[dc][j], sacc[rt][j]);
      }
    }

  const float scale = 0.125f;
  #pragma unroll
  for (int rt = 0; rt < 2; ++rt)
    #pragma unroll
    for (int r = 0; r < 4; ++r) {
      float v0 = sacc[rt][0][r] * scale, v1 = sacc[rt][1][r] * scale;
      float v2 = sacc[rt][2][r] * scale, v3 = sacc[rt][3][r] * scale;
      float mx = fmaxf(fmaxf(v0, v1), fmaxf(v2, v3));
      #pragma unroll
      for (int off = 1; off < 16; off <<= 1)
        mx = fmaxf(mx, __shfl_xor(mx, off, 64));
      float e0 = __expf(v0 - mx), e1 = __expf(v1 - mx);
      float e2 = __expf(v2 - mx), e3 = __expf(v3 - mx);
      float sm = e0 + e1 + e2 + e3;
      #pragma unroll
      for (int off = 1; off < 16; off <<= 1)
        sm += __shfl_xor(sm, off, 64);
      float inv = 1.0f / sm;
      int prow = rt * 16 + quad * 4 + r;
      Plds[wave][prow][ 0 + l16] = f2bf(e0 * inv);
      Plds[wave][prow][16 + l16] = f2bf(e1 * inv);
      Plds[wave][prow][32 + l16] = f2bf(e2 * inv);
      Plds[wave][prow][48 + l16] = f2bf(e3 * inv);
    }
  __syncthreads();

  f32x4 oacc[2][4] = {};
  #pragma unroll
  for (int rt = 0; rt < 2; ++rt)
    #pragma unroll
    for (int kc = 0; kc < 2; ++kc) {
      bf16x8 a = ldbf8(&Plds[wave][rt * 16 + l16][kc * 32 + quad * 8]);
      #pragma unroll
      for (int j = 0; j < 4; ++j) {
        bf16x8 bh_ = ldbf8(&VTh[j * 16 + l16][kc * 32 + quad * 8]);
        bf16x8 bl_ = ldbf8(&VTl[j * 16 + l16][kc * 32 + quad * 8]);
        oacc[rt][j] = mfma16(a, bh_, oacc[rt][j]);
        oacc[rt][j] = mfma16(a, bl_, oacc[rt][j]);
      }
    }

  #pragma unroll
  for (int rt = 0; rt < 2; ++rt)
    #pragma unroll
    for (int j = 0; j < 4; ++j)
      #pragma unroll
      for (int r = 0; r < 4; ++r) {
        int n = n_base + rt * 16 + quad * 4 + r;
        ctx[((size_t)(n * DIMB + b) << 10) + h * DH + j * 16 + l16] = f2bf(oacc[rt][j][r]);
      }
}

// ---------------- 128x128 bf16 MFMA GEMM (final projection, DMA dbuf staging) ----------------
__global__ __launch_bounds__(256) void gemm128_out(
    const unsigned short* __restrict__ A, const unsigned short* __restrict__ Bt,
    const float* __restrict__ bias, float* __restrict__ outF)
{
  __shared__ unsigned short As0[128 * 32], As1[128 * 32];
  __shared__ unsigned short Bs0[128 * 32], Bs1[128 * 32];
  const int tid  = threadIdx.x;
  const int wave = tid >> 6, lane = tid & 63;
  const int quad = lane >> 4, l16 = lane & 15;
  const int wm = (wave >> 1) * 64, wn = (wave & 1) * 64;
  const int m0 = blockIdx.x * 128, n0 = blockIdx.y * 128;
  const unsigned short* Ab = A  + (size_t)m0 * 1024;
  const unsigned short* Bb = Bt + (size_t)n0 * 1024;

  f32x4 acc[4][4] = {};

  stage_tile(Ab, 1024, As0, tid, 0);
  stage_tile(Bb, 1024, Bs0, tid, 0);
  __syncthreads();
  int cur = 0;
  for (int t = 0; t < 32; ++t) {
    const unsigned short* Ac = cur ? As1 : As0;
    const unsigned short* Bc = cur ? Bs1 : Bs0;
    unsigned short* An = cur ? As0 : As1;
    unsigned short* Bn = cur ? Bs0 : Bs1;
    bf16x8 af[4], bfr[4];
    #pragma unroll
    for (int i = 0; i < 4; ++i) af[i]  = ldbf8(frag_ptr(Ac, wm + 16 * i + l16, quad));
    #pragma unroll
    for (int j = 0; j < 4; ++j) bfr[j] = ldbf8(frag_ptr(Bc, wn + 16 * j + l16, quad));
    if (t < 31) {
      stage_tile(Ab, 1024, An, tid, (t + 1) * 32);
      stage_tile(Bb, 1024, Bn, tid, (t + 1) * 32);
    }
    #pragma unroll
    for (int i = 0; i < 4; ++i)
      #pragma unroll
      for (int j = 0; j < 4; ++j)
        acc[i][j] = mfma16(af[i], bfr[j], acc[i][j]);
    if (t < 31) __syncthreads();
    cur ^= 1;
  }

  #pragma unroll
  for (int i = 0; i < 4; ++i)
    #pragma unroll
    for (int j = 0; j < 4; ++j) {
      int col = n0 + wn + 16 * j + l16;
      float bs = bias[col];
      #pragma unroll
      for (int r = 0; r < 4; ++r) {
        int row = m0 + wm + 16 * i + quad * 4 + r;
        outF[(size_t)row * 1024 + col] = acc[i][j][r] + bs;
      }
    }
}

// ---------------- launch ----------------
extern "C" void kernel_launch(void* const* d_in, const int* in_sizes, int n_in,
                              void* d_out, int out_size, void* d_ws, size_t ws_size,
                              hipStream_t stream) {
  const float* x    = (const float*)d_in[0];
  const float* E    = (const float*)d_in[1];
  const float* F    = (const float*)d_in[2];
  const float* Wqkv = (const float*)d_in[3];
  const float* bqkv = (const float*)d_in[4];
  const float* Wout = (const float*)d_in[5];
  const float* bout = (const float*)d_in[6];
  float* out = (float*)d_out;

  const size_t MB = 1024 * 1024;
  char* ws = (char*)d_ws;
  // ---- workspace: ~81.4 MB (<100 MB proven bound), phase-aliased ----
  unsigned short* qb    = (unsigned short*)ws;                  // [0,32) MB (phase B+C)
  float*          partQ = (float*)ws;                           // [0,16) MB (phase A, dead before qb)
  unsigned short* xf16  = (unsigned short*)(ws + 32 * MB);      // [32,64) MB (phase A+B)
  unsigned short* ctx   = (unsigned short*)(ws + 32 * MB);      // [32,64) alias after xf16 dies
  unsigned short* wqT   = (unsigned short*)(ws + 64 * MB);      // 2 MB
  unsigned short* WoutT = (unsigned short*)(ws + 66 * MB);      // 2 MB
  unsigned short* eft   = (unsigned short*)(ws + 68 * MB);      // 1 MB
  unsigned short* xEFh  = (unsigned short*)(ws + 69 * MB);      // 1 MB  [m512][k1024] bf16 hi
  unsigned short* xEFl  = (unsigned short*)(ws + 70 * MB);      // 1 MB  bf16 lo
  unsigned short* wkvh  = (unsigned short*)(ws + 71 * MB);      // 4 MB  [n2048][k1024] bf16 hi
  unsigned short* wkvl  = (unsigned short*)(ws + 75 * MB);      // 4 MB  bf16 lo
  float*          sEF   = (float*)(ws + 79 * MB);               // 512 B
  float*          klow  = (float*)(ws + 79 * MB + 65536);       // 1 MB
  float*          vlow  = (float*)(ws + 80 * MB + 65536);       // 1 MB
  float*          partS = (float*)(ws + 81 * MB + 65536);       // 8 KB (colsum partials)

  // phase A: fp16 casts; E^T x / F^T x as split-K fp16 MFMA GEMM (partials in dead qb region);
  //          K/V projection as 3-product bf16 MFMA GEMM.
  transpose_wq_f16<<<dim3(32, 32), dim3(32, 8), 0, stream>>>(Wqkv, wqT);
  cast_x_f16<<<dim3(2048), dim3(256), 0, stream>>>(x, xf16);
  transpose_EF_f16<<<dim3(2, 128, 2), dim3(32, 8), 0, stream>>>(E, F, eft);
  transpose_split_wkv<<<dim3(64, 32), dim3(32, 8), 0, stream>>>(Wqkv, wkvh, wkvl);
  gemm_xEF<<<dim3(32, 8), dim3(256), 0, stream>>>(xf16, eft, partQ);
  reduce_xEF2<<<dim3(2048), dim3(256), 0, stream>>>(partQ, xEFh, xEFl);
  colsum_EF1<<<dim3(2, 16), dim3(256), 0, stream>>>(E, F, partS);
  colsum_EF2<<<dim3(1), dim3(128), 0, stream>>>(partS, sEF);
  gemm_klv<<<dim3(8, 4), dim3(256), 0, stream>>>(xEFh, xEFl, wkvh, wkvl, bqkv, sEF, klow, vlow);

  // phase B: q GEMM (overwrites partQ region with qb; xf16 dies after)
  gemm_q_f16<<<dim3(128, 8), dim3(256), 0, stream>>>(xf16, wqT, bqkv, qb);

  // phase C: attention + output projection (ctx over dead xf16)
  transpose_cast<<<dim3(32, 32), dim3(32, 8), 0, stream>>>(Wout, WoutT, 1024, 1024);
  attn_fused<<<dim3(64, 32), dim3(256), 0, stream>>>(qb, klow, vlow, ctx);
  gemm128_out<<<dim3(128, 8), dim3(256), 0, stream>>>(ctx, WoutT, bout, out);
}

// Round 9
// 356.900 us; speedup vs baseline: 1.0316x; 1.0316x over previous
//
#include <hip/hip_runtime.h>

#define DIMN 4096
#define DIMB 4
#define DIMH 16
#define DIMK 64
#define DH   64

typedef __attribute__((ext_vector_type(8))) __bf16 bf16x8;
typedef __attribute__((ext_vector_type(8))) _Float16 f16x8;
typedef __attribute__((ext_vector_type(8))) unsigned short u16x8;
typedef __attribute__((ext_vector_type(4))) float f32x4;
typedef __attribute__((ext_vector_type(4))) int i32x4;

__device__ __forceinline__ unsigned short f2bf(float f) {
  union { float f; unsigned u; } v; v.f = f;
  unsigned r = v.u + 0x7FFFu + ((v.u >> 16) & 1u);
  return (unsigned short)(r >> 16);
}
__device__ __forceinline__ float bf2f(unsigned short u) {
  union { unsigned u; float f; } v; v.u = ((unsigned)u) << 16; return v.f;
}
// split f32 -> (hi, lo) bf16 pair: hi+lo ~ f with ~2^-17 rel error
__device__ __forceinline__ void split2(float f, unsigned short& h, unsigned short& l) {
  h = f2bf(f);
  l = f2bf(f - bf2f(h));
}
__device__ __forceinline__ unsigned short f2h(float f) {
  _Float16 h = (_Float16)f;
  return __builtin_bit_cast(unsigned short, h);
}
__device__ __forceinline__ bf16x8 ldbf8(const unsigned short* p) {
  return __builtin_bit_cast(bf16x8, *(const u16x8*)p);
}
__device__ __forceinline__ f16x8 ldh8(const unsigned short* p) {
  return __builtin_bit_cast(f16x8, *(const u16x8*)p);
}
__device__ __forceinline__ f32x4 mfma16(bf16x8 a, bf16x8 b, f32x4 c) {
  return __builtin_amdgcn_mfma_f32_16x16x32_bf16(a, b, c, 0, 0, 0);
}
__device__ __forceinline__ f32x4 mfma16h(f16x8 a, f16x8 b, f32x4 c) {
  return __builtin_amdgcn_mfma_f32_16x16x32_f16(a, b, c, 0, 0, 0);
}

// ---- global->LDS direct DMA, 16B per lane; LDS dest is wave-uniform base + lane*16 ----
__device__ __forceinline__ void gl_lds16(const unsigned short* g, unsigned short* l) {
  __builtin_amdgcn_global_load_lds(
      (const __attribute__((address_space(1))) unsigned int*)g,
      (__attribute__((address_space(3))) unsigned int*)l, 16, 0, 0);
}

// Stage a [128][32]-ushort tile (linear LDS, 64B rows) from row-major src (stride elems).
// XOR-swizzled source slot f(row)=(row>>1)&3: LDS[row][slot] holds global slot (slot^f).
// 16B-unit = (row&1)*4 + quad^f(row): 16 consecutive rows cover all 8 units twice -> 2-way (free).
// Reads must use frag_ptr below (same involution). [guide §5 rule 21, §6 G4; r8: conflicts=0]
__device__ __forceinline__ void stage_tile(const unsigned short* src, int stride,
                                           unsigned short* lds, int tid, int k0) {
  const int wave = tid >> 6;
  #pragma unroll
  for (int s = 0; s < 2; ++s) {
    int idx = tid + s * 256;
    int row = idx >> 2;
    int slot = idx & 3;
    gl_lds16(&src[(size_t)row * stride + k0 + ((slot ^ ((row >> 1) & 3)) * 8)],
             &lds[(size_t)(s * 256 + wave * 64) * 8]);
  }
}
__device__ __forceinline__ const unsigned short* frag_ptr(const unsigned short* lds,
                                                          int row, int quad) {
  return &lds[row * 32 + ((quad ^ ((row >> 1) & 3)) * 8)];
}

// ------------- transpose + cast: src (R,C) f32 -> dst (C,R) bf16 [PROVEN r3] -------------
__global__ void transpose_cast(const float* __restrict__ src, unsigned short* __restrict__ dst,
                               int R, int C) {
  __shared__ float tile[32][33];
  int c0 = blockIdx.x * 32, r0 = blockIdx.y * 32;
  for (int i = threadIdx.y; i < 32; i += 8)
    tile[i][threadIdx.x] = src[(size_t)(r0 + i) * C + c0 + threadIdx.x];
  __syncthreads();
  for (int i = threadIdx.y; i < 32; i += 8)
    dst[(size_t)(c0 + i) * R + r0 + threadIdx.x] = f2bf(tile[threadIdx.x][i]);
}

// ------------- transpose + cast fp16 of Wqkv[:, :1024] -> WqT (1024x1024, [n][k]) -------------
__global__ void transpose_wq_f16(const float* __restrict__ W, unsigned short* __restrict__ t) {
  __shared__ float tile[32][33];
  int c0 = blockIdx.x * 32, r0 = blockIdx.y * 32;   // c: n (col of Wq), r: k (row of Wq)
  for (int i = threadIdx.y; i < 32; i += 8)
    tile[i][threadIdx.x] = W[(size_t)(r0 + i) * 3072 + c0 + threadIdx.x];
  __syncthreads();
  for (int i = threadIdx.y; i < 32; i += 8)
    t[(size_t)(c0 + i) * 1024 + r0 + threadIdx.x] = f2h(tile[threadIdx.x][i]);
}

// ------------- transpose + hi/lo split of Wqkv[:, 1024:3072] -> WkvT (2048 x 1024, [n][k]) -------------
__global__ void transpose_split_wkv(const float* __restrict__ W,
                                    unsigned short* __restrict__ th,
                                    unsigned short* __restrict__ tl) {
  __shared__ float tile[32][33];
  int c0 = blockIdx.x * 32, r0 = blockIdx.y * 32;   // c: 0..2047 (col-1024), r: k
  for (int i = threadIdx.y; i < 32; i += 8)
    tile[i][threadIdx.x] = W[(size_t)(r0 + i) * 3072 + 1024 + c0 + threadIdx.x];
  __syncthreads();
  for (int i = threadIdx.y; i < 32; i += 8) {
    float v = tile[threadIdx.x][i];
    unsigned short h, l; split2(v, h, l);
    size_t o = (size_t)(c0 + i) * 1024 + r0 + threadIdx.x;
    th[o] = h;
    tl[o] = l;
  }
}

// ------------- transpose + cast fp16 of E,F (4096x64) -> EFt (128 kk x 4096 n) -------------
__global__ void transpose_EF_f16(const float* __restrict__ E, const float* __restrict__ F,
                                 unsigned short* __restrict__ t) {
  __shared__ float tile[32][33];
  const float* src = blockIdx.z ? F : E;
  const int kkbase = blockIdx.z * 64;
  int c0 = blockIdx.x * 32, r0 = blockIdx.y * 32;   // c: k-col of E, r: n
  for (int i = threadIdx.y; i < 32; i += 8)
    tile[i][threadIdx.x] = src[(size_t)(r0 + i) * 64 + c0 + threadIdx.x];
  __syncthreads();
  for (int i = threadIdx.y; i < 32; i += 8)
    t[(size_t)(kkbase + c0 + i) * 4096 + r0 + threadIdx.x] = f2h(tile[threadIdx.x][i]);
}

// ------------- cast x (16M f32) -> fp16 (memory-bound, vectorized) -------------
__global__ __launch_bounds__(256) void cast_x_f16(
    const float* __restrict__ src, unsigned short* __restrict__ d) {
  const int total4 = DIMN * DIMB * 1024 / 4;   // 4,194,304 float4s
  int i = blockIdx.x * 256 + threadIdx.x;
  const int stride = gridDim.x * 256;
  for (; i < total4; i += stride) {
    float4 v = ((const float4*)src)[i];
    ushort4 h;
    h.x = f2h(v.x); h.y = f2h(v.y); h.z = f2h(v.z); h.w = f2h(v.w);
    ((ushort4*)d)[i] = h;
  }
}

// ------------- fp16 MFMA GEMM for q (DMA staging, single-buffer [r7-proven], swizzled LDS) -------------
// q(16384x1024) = x @ Wq + bq ; scatter q (b,h,n,d) bf16. A=[m][k] fp16, Bt=[n][k] fp16.
__global__ __launch_bounds__(256) void gemm_q_f16(
    const unsigned short* __restrict__ A, const unsigned short* __restrict__ Bt,
    const float* __restrict__ bias, unsigned short* __restrict__ q)
{
  __shared__ unsigned short As[128 * 32];
  __shared__ unsigned short Bs[128 * 32];
  const int tid  = threadIdx.x;
  const int wave = tid >> 6, lane = tid & 63;
  const int quad = lane >> 4, l16 = lane & 15;
  const int wm = (wave >> 1) * 64, wn = (wave & 1) * 64;
  const int m0 = blockIdx.x * 128, n0 = blockIdx.y * 128;
  const unsigned short* Ab = A  + (size_t)m0 * 1024;
  const unsigned short* Bb = Bt + (size_t)n0 * 1024;

  f32x4 acc[4][4] = {};

  for (int k0 = 0; k0 < 1024; k0 += 32) {
    stage_tile(Ab, 1024, As, tid, k0);
    stage_tile(Bb, 1024, Bs, tid, k0);
    __syncthreads();   // drains vmcnt(0) -> DMA complete
    f16x8 af[4], bfr[4];
    #pragma unroll
    for (int i = 0; i < 4; ++i) af[i]  = ldh8(frag_ptr(As, wm + 16 * i + l16, quad));
    #pragma unroll
    for (int j = 0; j < 4; ++j) bfr[j] = ldh8(frag_ptr(Bs, wn + 16 * j + l16, quad));
    #pragma unroll
    for (int i = 0; i < 4; ++i)
      #pragma unroll
      for (int j = 0; j < 4; ++j)
        acc[i][j] = mfma16h(af[i], bfr[j], acc[i][j]);
    __syncthreads();
  }

  #pragma unroll
  for (int i = 0; i < 4; ++i)
    #pragma unroll
    for (int j = 0; j < 4; ++j) {
      int col = n0 + wn + 16 * j + l16;     // 0..1023 (q cols)
      float bs = bias[col];
      int h = col >> 6, d = col & 63;
      #pragma unroll
      for (int r = 0; r < 4; ++r) {
        int row = m0 + wm + 16 * i + quad * 4 + r;
        int n = row >> 2, b = row & 3;      // x row-major (N,B,DIM): row = n*4+b
        q[(((size_t)(b * DIMH + h) * DIMN + n) << 6) + d] = f2bf(acc[i][j][r] + bs);
      }
    }
}

// ------------- split-K fp16 MFMA GEMM: partial[ks][kk128][c4096] = EFt[kk][n] . x[n][c] -------------
__global__ __launch_bounds__(256) void gemm_xEF(
    const unsigned short* __restrict__ xf, const unsigned short* __restrict__ ef,
    float* __restrict__ partial)
{
  __shared__ unsigned short Ash[128 * 40];
  __shared__ unsigned short Bsh[128 * 40];
  const int tid  = threadIdx.x;
  const int wave = tid >> 6, lane = tid & 63;
  const int quad = lane >> 4, l16 = lane & 15;
  const int wm = (wave >> 1) * 64, wn = (wave & 1) * 64;
  const int c0 = blockIdx.x * 128;
  const int ks = blockIdx.y;

  f32x4 acc[4][4] = {};

  const int kend = ks * 512 + 512;
  for (int k0 = ks * 512; k0 < kend; k0 += 32) {
    #pragma unroll
    for (int s = 0; s < 2; ++s) {
      int idx = tid + s * 256;
      int row = idx >> 2;             // kk 0..127
      int kc  = (idx & 3) * 8;        // n-local 0..31
      *(i32x4*)&Ash[row * 40 + kc] = *(const i32x4*)&ef[(size_t)row * 4096 + k0 + kc];
    }
    // B staging: LDS transpose-scatter x[n][c] -> Bs[c][n]
    #pragma unroll
    for (int s = 0; s < 2; ++s) {
      int n_l = tid & 31;
      int c8  = (tid >> 5) + s * 8;   // 0..15
      u16x8 vh = *(const u16x8*)&xf[(size_t)(k0 + n_l) * 4096 + c0 + c8 * 8];
      #pragma unroll
      for (int e = 0; e < 8; ++e)
        Bsh[(c8 * 8 + e) * 40 + n_l] = vh[e];
    }
    __syncthreads();
    f16x8 afh[4], bfh[4];
    #pragma unroll
    for (int i = 0; i < 4; ++i) afh[i] = ldh8(&Ash[(wm + 16 * i + l16) * 40 + quad * 8]);
    #pragma unroll
    for (int j = 0; j < 4; ++j) bfh[j] = ldh8(&Bsh[(wn + 16 * j + l16) * 40 + quad * 8]);
    #pragma unroll
    for (int i = 0; i < 4; ++i)
      #pragma unroll
      for (int j = 0; j < 4; ++j)
        acc[i][j] = mfma16h(afh[i], bfh[j], acc[i][j]);
    __syncthreads();
  }

  #pragma unroll
  for (int i = 0; i < 4; ++i)
    #pragma unroll
    for (int j = 0; j < 4; ++j) {
      int col = c0 + wn + 16 * j + l16;
      #pragma unroll
      for (int r = 0; r < 4; ++r) {
        int m = wm + 16 * i + quad * 4 + r;   // kk' 0..127
        partial[((size_t)ks * 128 + m) * 4096 + col] = acc[i][j][r];
      }
    }
}

// ------------- reduce split-K partials -> xEF bf16 hi/lo in [m][k] GEMM layout -------------
// m = t*256 + b*64 + (kk&63), k = c&1023  (t = kk>>6, b = c>>10)
__global__ __launch_bounds__(256) void reduce_xEF2(
    const float* __restrict__ partial, unsigned short* __restrict__ xh,
    unsigned short* __restrict__ xl)
{
  int t_lin = blockIdx.x * 256 + threadIdx.x;   // kk*4096 + c
  float s = 0.f;
  #pragma unroll
  for (int ks = 0; ks < 8; ++ks)
    s += partial[(size_t)ks * 524288 + t_lin];
  int kk = t_lin >> 12, c = t_lin & 4095;
  int t = kk >> 6, kkl = kk & 63, b = c >> 10, k = c & 1023;
  int m = t * 256 + b * 64 + kkl;
  unsigned short h, l; split2(s, h, l);
  xh[m * 1024 + k] = h;
  xl[m * 1024 + k] = l;
}

// ------------- column sums of E,F stage 1: partS[src][chunk16][kk64] -------------
__global__ __launch_bounds__(256) void colsum_EF1(
    const float* __restrict__ E, const float* __restrict__ F,
    float* __restrict__ partS)
{
  const int src = blockIdx.x;          // 0..1
  const int ch  = blockIdx.y;          // 0..15
  const float* S = src ? F : E;
  const int r  = threadIdx.x >> 6;     // 0..3
  const int kk = threadIdx.x & 63;
  const int n0 = ch * 256;
  float s = 0.f;
  #pragma unroll 8
  for (int i = 0; i < 64; ++i)
    s += S[(size_t)(n0 + r + 4 * i) * 64 + kk];
  __shared__ float red[4][64];
  red[r][kk] = s;
  __syncthreads();
  if (r == 0)
    partS[((size_t)src * 16 + ch) * 64 + kk] = red[0][kk] + red[1][kk] + red[2][kk] + red[3][kk];
}

// ------------- column sums stage 2: sEF[src*64+kk] = sum_ch partS -------------
__global__ void colsum_EF2(const float* __restrict__ partS, float* __restrict__ sEF) {
  int t = threadIdx.x;                 // 0..127
  int src = t >> 6, kk = t & 63;
  float s = 0.f;
  #pragma unroll
  for (int ch = 0; ch < 16; ++ch)
    s += partS[((size_t)src * 16 + ch) * 64 + kk];
  sEF[t] = s;
}

// ------------- klow/vlow via 3-product bf16 MFMA GEMM (M=512, N=1024, K=1024) -------------
// A = xEF hi/lo [m][k] (m = t*256+b*64+kk); B = WkvT hi/lo [t*1024+c][k].
// global_load_lds staging + swizzled LDS. Epilogue adds sEF[kk]*bias, scatters fp32.
__global__ __launch_bounds__(256) void gemm_klv(
    const unsigned short* __restrict__ Ah, const unsigned short* __restrict__ Al,
    const unsigned short* __restrict__ Bh, const unsigned short* __restrict__ Bl,
    const float* __restrict__ bias, const float* __restrict__ sEF,
    float* __restrict__ klow, float* __restrict__ vlow)
{
  __shared__ unsigned short Ash[128 * 32], Asl[128 * 32];
  __shared__ unsigned short Bsh[128 * 32], Bsl[128 * 32];
  const int tid  = threadIdx.x;
  const int wave = tid >> 6, lane = tid & 63;
  const int quad = lane >> 4, l16 = lane & 15;
  const int wm = (wave >> 1) * 64, wn = (wave & 1) * 64;
  const int mt = blockIdx.y;           // 0..3
  const int t  = mt >> 1;
  const int m0 = mt * 128;
  const int n0 = blockIdx.x * 128;     // c-tile within t
  const int brow = t * 1024 + n0;
  const unsigned short* Ahb = Ah + (size_t)m0 * 1024;
  const unsigned short* Alb = Al + (size_t)m0 * 1024;
  const unsigned short* Bhb = Bh + (size_t)brow * 1024;
  const unsigned short* Blb = Bl + (size_t)brow * 1024;

  f32x4 acc[4][4] = {};

  for (int k0 = 0; k0 < 1024; k0 += 32) {
    stage_tile(Ahb, 1024, Ash, tid, k0);
    stage_tile(Alb, 1024, Asl, tid, k0);
    stage_tile(Bhb, 1024, Bsh, tid, k0);
    stage_tile(Blb, 1024, Bsl, tid, k0);
    __syncthreads();
    bf16x8 afh[4], afl[4], bfh[4], bfl[4];
    #pragma unroll
    for (int i = 0; i < 4; ++i) {
      afh[i] = ldbf8(frag_ptr(Ash, wm + 16 * i + l16, quad));
      afl[i] = ldbf8(frag_ptr(Asl, wm + 16 * i + l16, quad));
    }
    #pragma unroll
    for (int j = 0; j < 4; ++j) {
      bfh[j] = ldbf8(frag_ptr(Bsh, wn + 16 * j + l16, quad));
      bfl[j] = ldbf8(frag_ptr(Bsl, wn + 16 * j + l16, quad));
    }
    #pragma unroll
    for (int i = 0; i < 4; ++i)
      #pragma unroll
      for (int j = 0; j < 4; ++j) {
        acc[i][j] = mfma16(afh[i], bfh[j], acc[i][j]);
        acc[i][j] = mfma16(afh[i], bfl[j], acc[i][j]);
        acc[i][j] = mfma16(afl[i], bfh[j], acc[i][j]);
      }
    __syncthreads();
  }

  float* dstb = (t ? vlow : klow);
  #pragma unroll
  for (int i = 0; i < 4; ++i)
    #pragma unroll
    for (int j = 0; j < 4; ++j) {
      int c = n0 + wn + 16 * j + l16;       // 0..1023
      int h = c >> 6, d = c & 63;
      float bs = bias[1024 * (1 + t) + c];
      #pragma unroll
      for (int r = 0; r < 4; ++r) {
        int m = m0 + wm + 16 * i + quad * 4 + r;
        int b = (m >> 6) & 3, kk = m & 63;
        float val = acc[i][j][r] + sEF[t * 64 + kk] * bs;
        dstb[(((size_t)b * DIMH + h) * DIMK + kk) * DH + d] = val;
      }
    }
}

// ------------- fused dots -> softmax -> PV -------------
// KL/VL fp32; K and V split hi/lo bf16 for MFMA (near-fp32 logits & PV).
__global__ __launch_bounds__(256) void attn_fused(
    const unsigned short* __restrict__ qb, const float* __restrict__ klow,
    const float* __restrict__ vlow, unsigned short* __restrict__ ctx)
{
  __shared__ unsigned short VTh[64][72], VTl[64][72];  // [d][k], k<72
  __shared__ unsigned short Plds[4][32][72];
  const int bh = blockIdx.x, b = bh >> 4, h = bh & 15;
  const unsigned short* Q  = qb   + (size_t)bh * DIMN * DH;
  const float* KL = klow + (size_t)bh * DIMK * DH;
  const float* VL = vlow + (size_t)bh * DIMK * DH;
  const int tid = threadIdx.x, wave = tid >> 6, lane = tid & 63;
  const int quad = lane >> 4, l16 = lane & 15;

  #pragma unroll
  for (int it = 0; it < 2; ++it) {
    int idx = tid + it * 256;
    int kk = idx >> 3, d0 = (idx & 7) * 8;
    float4 f0 = *(const float4*)&VL[kk * DH + d0];
    float4 f1 = *(const float4*)&VL[kk * DH + d0 + 4];
    float vv[8] = {f0.x, f0.y, f0.z, f0.w, f1.x, f1.y, f1.z, f1.w};
    #pragma unroll
    for (int e = 0; e < 8; ++e) {
      unsigned short hh, ll;
      split2(vv[e], hh, ll);
      VTh[d0 + e][kk] = hh;
      VTl[d0 + e][kk] = ll;
    }
  }
  bf16x8 kfh[2][4], kfl[2][4];
  #pragma unroll
  for (int dc = 0; dc < 2; ++dc)
    #pragma unroll
    for (int j = 0; j < 4; ++j) {
      const float* p = &KL[(j * 16 + l16) * DH + dc * 32 + quad * 8];
      float4 f0 = *(const float4*)p;
      float4 f1 = *(const float4*)(p + 4);
      float vv[8] = {f0.x, f0.y, f0.z, f0.w, f1.x, f1.y, f1.z, f1.w};
      alignas(16) unsigned short th[8], tl[8];
      #pragma unroll
      for (int e = 0; e < 8; ++e) split2(vv[e], th[e], tl[e]);
      kfh[dc][j] = ldbf8(th);
      kfl[dc][j] = ldbf8(tl);
    }
  __syncthreads();

  const int n_base = blockIdx.y * 128 + wave * 32;

  f32x4 sacc[2][4] = {};
  #pragma unroll
  for (int rt = 0; rt < 2; ++rt)
    #pragma unroll
    for (int dc = 0; dc < 2; ++dc) {
      bf16x8 a = ldbf8(&Q[(size_t)(n_base + rt * 16 + l16) * DH + dc * 32 + quad * 8]);
      #pragma unroll
      for (int j = 0; j < 4; ++j) {
        sacc[rt][j] = mfma16(a, kfh[dc][j], sacc[rt][j]);
        sacc[rt][j] = mfma16(a, kfl[dc][j], sacc[rt][j]);
      }
    }

  const float scale = 0.125f;
  #pragma unroll
  for (int rt = 0; rt < 2; ++rt)
    #pragma unroll
    for (int r = 0; r < 4; ++r) {
      float v0 = sacc[rt][0][r] * scale, v1 = sacc[rt][1][r] * scale;
      float v2 = sacc[rt][2][r] * scale, v3 = sacc[rt][3][r] * scale;
      float mx = fmaxf(fmaxf(v0, v1), fmaxf(v2, v3));
      #pragma unroll
      for (int off = 1; off < 16; off <<= 1)
        mx = fmaxf(mx, __shfl_xor(mx, off, 64));
      float e0 = __expf(v0 - mx), e1 = __expf(v1 - mx);
      float e2 = __expf(v2 - mx), e3 = __expf(v3 - mx);
      float sm = e0 + e1 + e2 + e3;
      #pragma unroll
      for (int off = 1; off < 16; off <<= 1)
        sm += __shfl_xor(sm, off, 64);
      float inv = 1.0f / sm;
      int prow = rt * 16 + quad * 4 + r;
      Plds[wave][prow][ 0 + l16] = f2bf(e0 * inv);
      Plds[wave][prow][16 + l16] = f2bf(e1 * inv);
      Plds[wave][prow][32 + l16] = f2bf(e2 * inv);
      Plds[wave][prow][48 + l16] = f2bf(e3 * inv);
    }
  __syncthreads();

  f32x4 oacc[2][4] = {};
  #pragma unroll
  for (int rt = 0; rt < 2; ++rt)
    #pragma unroll
    for (int kc = 0; kc < 2; ++kc) {
      bf16x8 a = ldbf8(&Plds[wave][rt * 16 + l16][kc * 32 + quad * 8]);
      #pragma unroll
      for (int j = 0; j < 4; ++j) {
        bf16x8 bh_ = ldbf8(&VTh[j * 16 + l16][kc * 32 + quad * 8]);
        bf16x8 bl_ = ldbf8(&VTl[j * 16 + l16][kc * 32 + quad * 8]);
        oacc[rt][j] = mfma16(a, bh_, oacc[rt][j]);
        oacc[rt][j] = mfma16(a, bl_, oacc[rt][j]);
      }
    }

  #pragma unroll
  for (int rt = 0; rt < 2; ++rt)
    #pragma unroll
    for (int j = 0; j < 4; ++j)
      #pragma unroll
      for (int r = 0; r < 4; ++r) {
        int n = n_base + rt * 16 + quad * 4 + r;
        ctx[((size_t)(n * DIMB + b) << 10) + h * DH + j * 16 + l16] = f2bf(oacc[rt][j][r]);
      }
}

// ---------------- 128x128 bf16 MFMA GEMM (final projection, DMA single-buffer [r7-proven]) ----------------
__global__ __launch_bounds__(256) void gemm128_out(
    const unsigned short* __restrict__ A, const unsigned short* __restrict__ Bt,
    const float* __restrict__ bias, float* __restrict__ outF)
{
  __shared__ unsigned short As[128 * 32];
  __shared__ unsigned short Bs[128 * 32];
  const int tid  = threadIdx.x;
  const int wave = tid >> 6, lane = tid & 63;
  const int quad = lane >> 4, l16 = lane & 15;
  const int wm = (wave >> 1) * 64, wn = (wave & 1) * 64;
  const int m0 = blockIdx.x * 128, n0 = blockIdx.y * 128;
  const unsigned short* Ab = A  + (size_t)m0 * 1024;
  const unsigned short* Bb = Bt + (size_t)n0 * 1024;

  f32x4 acc[4][4] = {};

  for (int k0 = 0; k0 < 1024; k0 += 32) {
    stage_tile(Ab, 1024, As, tid, k0);
    stage_tile(Bb, 1024, Bs, tid, k0);
    __syncthreads();
    bf16x8 af[4], bfr[4];
    #pragma unroll
    for (int i = 0; i < 4; ++i) af[i]  = ldbf8(frag_ptr(As, wm + 16 * i + l16, quad));
    #pragma unroll
    for (int j = 0; j < 4; ++j) bfr[j] = ldbf8(frag_ptr(Bs, wn + 16 * j + l16, quad));
    #pragma unroll
    for (int i = 0; i < 4; ++i)
      #pragma unroll
      for (int j = 0; j < 4; ++j)
        acc[i][j] = mfma16(af[i], bfr[j], acc[i][j]);
    __syncthreads();
  }

  #pragma unroll
  for (int i = 0; i < 4; ++i)
    #pragma unroll
    for (int j = 0; j < 4; ++j) {
      int col = n0 + wn + 16 * j + l16;
      float bs = bias[col];
      #pragma unroll
      for (int r = 0; r < 4; ++r) {
        int row = m0 + wm + 16 * i + quad * 4 + r;
        outF[(size_t)row * 1024 + col] = acc[i][j][r] + bs;
      }
    }
}

// ---------------- launch ----------------
extern "C" void kernel_launch(void* const* d_in, const int* in_sizes, int n_in,
                              void* d_out, int out_size, void* d_ws, size_t ws_size,
                              hipStream_t stream) {
  const float* x    = (const float*)d_in[0];
  const float* E    = (const float*)d_in[1];
  const float* F    = (const float*)d_in[2];
  const float* Wqkv = (const float*)d_in[3];
  const float* bqkv = (const float*)d_in[4];
  const float* Wout = (const float*)d_in[5];
  const float* bout = (const float*)d_in[6];
  float* out = (float*)d_out;

  const size_t MB = 1024 * 1024;
  char* ws = (char*)d_ws;
  // ---- workspace: ~81.4 MB (<100 MB proven bound), phase-aliased ----
  unsigned short* qb    = (unsigned short*)ws;                  // [0,32) MB (phase B+C)
  float*          partQ = (float*)ws;                           // [0,16) MB (phase A, dead before qb)
  unsigned short* xf16  = (unsigned short*)(ws + 32 * MB);      // [32,64) MB (phase A+B)
  unsigned short* ctx   = (unsigned short*)(ws + 32 * MB);      // [32,64) alias after xf16 dies
  unsigned short* wqT   = (unsigned short*)(ws + 64 * MB);      // 2 MB
  unsigned short* WoutT = (unsigned short*)(ws + 66 * MB);      // 2 MB
  unsigned short* eft   = (unsigned short*)(ws + 68 * MB);      // 1 MB
  unsigned short* xEFh  = (unsigned short*)(ws + 69 * MB);      // 1 MB  [m512][k1024] bf16 hi
  unsigned short* xEFl  = (unsigned short*)(ws + 70 * MB);      // 1 MB  bf16 lo
  unsigned short* wkvh  = (unsigned short*)(ws + 71 * MB);      // 4 MB  [n2048][k1024] bf16 hi
  unsigned short* wkvl  = (unsigned short*)(ws + 75 * MB);      // 4 MB  bf16 lo
  float*          sEF   = (float*)(ws + 79 * MB);               // 512 B
  float*          klow  = (float*)(ws + 79 * MB + 65536);       // 1 MB
  float*          vlow  = (float*)(ws + 80 * MB + 65536);       // 1 MB
  float*          partS = (float*)(ws + 81 * MB + 65536);       // 8 KB (colsum partials)

  // phase A: fp16 casts; E^T x / F^T x as split-K fp16 MFMA GEMM (partials in dead qb region);
  //          K/V projection as 3-product bf16 MFMA GEMM.
  transpose_wq_f16<<<dim3(32, 32), dim3(32, 8), 0, stream>>>(Wqkv, wqT);
  cast_x_f16<<<dim3(2048), dim3(256), 0, stream>>>(x, xf16);
  transpose_EF_f16<<<dim3(2, 128, 2), dim3(32, 8), 0, stream>>>(E, F, eft);
  transpose_split_wkv<<<dim3(64, 32), dim3(32, 8), 0, stream>>>(Wqkv, wkvh, wkvl);
  gemm_xEF<<<dim3(32, 8), dim3(256), 0, stream>>>(xf16, eft, partQ);
  reduce_xEF2<<<dim3(2048), dim3(256), 0, stream>>>(partQ, xEFh, xEFl);
  colsum_EF1<<<dim3(2, 16), dim3(256), 0, stream>>>(E, F, partS);
  colsum_EF2<<<dim3(1), dim3(128), 0, stream>>>(partS, sEF);
  gemm_klv<<<dim3(8, 4), dim3(256), 0, stream>>>(xEFh, xEFl, wkvh, wkvl, bqkv, sEF, klow, vlow);

  // phase B: q GEMM (overwrites partQ region with qb; xf16 dies after)
  gemm_q_f16<<<dim3(128, 8), dim3(256), 0, stream>>>(xf16, wqT, bqkv, qb);

  // phase C: attention + output projection (ctx over dead xf16)
  transpose_cast<<<dim3(32, 32), dim3(32, 8), 0, stream>>>(Wout, WoutT, 1024, 1024);
  attn_fused<<<dim3(64, 32), dim3(256), 0, stream>>>(qb, klow, vlow, ctx);
  gemm128_out<<<dim3(128, 8), dim3(256), 0, stream>>>(ctx, WoutT, bout, out);
}

// Round 10
// 353.615 us; speedup vs baseline: 1.0412x; 1.0093x over previous
//
#include <hip/hip_runtime.h>

#define DIMN 4096
#define DIMB 4
#define DIMH 16
#define DIMK 64
#define DH   64

typedef __attribute__((ext_vector_type(8))) __bf16 bf16x8;
typedef __attribute__((ext_vector_type(8))) _Float16 f16x8;
typedef __attribute__((ext_vector_type(8))) unsigned short u16x8;
typedef __attribute__((ext_vector_type(4))) float f32x4;
typedef __attribute__((ext_vector_type(4))) int i32x4;

__device__ __forceinline__ unsigned short f2bf(float f) {
  union { float f; unsigned u; } v; v.f = f;
  unsigned r = v.u + 0x7FFFu + ((v.u >> 16) & 1u);
  return (unsigned short)(r >> 16);
}
__device__ __forceinline__ float bf2f(unsigned short u) {
  union { unsigned u; float f; } v; v.u = ((unsigned)u) << 16; return v.f;
}
// split f32 -> (hi, lo) bf16 pair: hi+lo ~ f with ~2^-17 rel error
__device__ __forceinline__ void split2(float f, unsigned short& h, unsigned short& l) {
  h = f2bf(f);
  l = f2bf(f - bf2f(h));
}
__device__ __forceinline__ unsigned short f2h(float f) {
  _Float16 h = (_Float16)f;
  return __builtin_bit_cast(unsigned short, h);
}
__device__ __forceinline__ bf16x8 ldbf8(const unsigned short* p) {
  return __builtin_bit_cast(bf16x8, *(const u16x8*)p);
}
__device__ __forceinline__ f16x8 ldh8(const unsigned short* p) {
  return __builtin_bit_cast(f16x8, *(const u16x8*)p);
}
__device__ __forceinline__ f32x4 mfma16(bf16x8 a, bf16x8 b, f32x4 c) {
  return __builtin_amdgcn_mfma_f32_16x16x32_bf16(a, b, c, 0, 0, 0);
}
__device__ __forceinline__ f32x4 mfma16h(f16x8 a, f16x8 b, f32x4 c) {
  return __builtin_amdgcn_mfma_f32_16x16x32_f16(a, b, c, 0, 0, 0);
}

// ---- global->LDS direct DMA, 16B per lane; LDS dest is wave-uniform base + lane*16 ----
__device__ __forceinline__ void gl_lds16(const unsigned short* g, unsigned short* l) {
  __builtin_amdgcn_global_load_lds(
      (const __attribute__((address_space(1))) unsigned int*)g,
      (__attribute__((address_space(3))) unsigned int*)l, 16, 0, 0);
}

// ---- BK=32 tile: [128][32] ushort, f(row)=(row>>1)&3 involution [r9-proven, conflicts=0] ----
__device__ __forceinline__ void stage_tile(const unsigned short* src, int stride,
                                           unsigned short* lds, int tid, int k0) {
  const int wave = tid >> 6;
  #pragma unroll
  for (int s = 0; s < 2; ++s) {
    int idx = tid + s * 256;
    int row = idx >> 2;
    int slot = idx & 3;
    gl_lds16(&src[(size_t)row * stride + k0 + ((slot ^ ((row >> 1) & 3)) * 8)],
             &lds[(size_t)(s * 256 + wave * 64) * 8]);
  }
}
__device__ __forceinline__ const unsigned short* frag_ptr(const unsigned short* lds,
                                                          int row, int quad) {
  return &lds[row * 32 + ((quad ^ ((row >> 1) & 3)) * 8)];
}

// ---- BK=64 tile: [128][64] ushort (128B rows, 8x16B units), involution f(row)=row&7.
// Per 16-lane quad-phase: chunk = slot^(row&7) covers all 8 units twice -> 2-way (free, m136).
// Halves barrier-drain count vs BK=32 (amortizes the vmcnt(0) serialization).
__device__ __forceinline__ void stage_tile64(const unsigned short* src, int stride,
                                             unsigned short* lds, int tid, int k0) {
  const int wave = tid >> 6;
  #pragma unroll
  for (int s = 0; s < 4; ++s) {
    int idx = tid + s * 256;
    int row = idx >> 3;
    int slot = idx & 7;
    gl_lds16(&src[(size_t)row * stride + k0 + ((slot ^ (row & 7)) * 8)],
             &lds[(size_t)(s * 256 + wave * 64) * 8]);
  }
}
__device__ __forceinline__ const unsigned short* frag_ptr64(const unsigned short* lds,
                                                            int row, int slot) {
  return &lds[row * 64 + ((slot ^ (row & 7)) * 8)];
}

// ------------- transpose + cast: src (R,C) f32 -> dst (C,R) bf16 [PROVEN r3] -------------
__global__ void transpose_cast(const float* __restrict__ src, unsigned short* __restrict__ dst,
                               int R, int C) {
  __shared__ float tile[32][33];
  int c0 = blockIdx.x * 32, r0 = blockIdx.y * 32;
  for (int i = threadIdx.y; i < 32; i += 8)
    tile[i][threadIdx.x] = src[(size_t)(r0 + i) * C + c0 + threadIdx.x];
  __syncthreads();
  for (int i = threadIdx.y; i < 32; i += 8)
    dst[(size_t)(c0 + i) * R + r0 + threadIdx.x] = f2bf(tile[threadIdx.x][i]);
}

// ------------- transpose + cast fp16 of Wqkv[:, :1024] -> WqT (1024x1024, [n][k]) -------------
__global__ void transpose_wq_f16(const float* __restrict__ W, unsigned short* __restrict__ t) {
  __shared__ float tile[32][33];
  int c0 = blockIdx.x * 32, r0 = blockIdx.y * 32;   // c: n (col of Wq), r: k (row of Wq)
  for (int i = threadIdx.y; i < 32; i += 8)
    tile[i][threadIdx.x] = W[(size_t)(r0 + i) * 3072 + c0 + threadIdx.x];
  __syncthreads();
  for (int i = threadIdx.y; i < 32; i += 8)
    t[(size_t)(c0 + i) * 1024 + r0 + threadIdx.x] = f2h(tile[threadIdx.x][i]);
}

// ------------- transpose + hi/lo split of Wqkv[:, 1024:3072] -> WkvT (2048 x 1024, [n][k]) -------------
__global__ void transpose_split_wkv(const float* __restrict__ W,
                                    unsigned short* __restrict__ th,
                                    unsigned short* __restrict__ tl) {
  __shared__ float tile[32][33];
  int c0 = blockIdx.x * 32, r0 = blockIdx.y * 32;   // c: 0..2047 (col-1024), r: k
  for (int i = threadIdx.y; i < 32; i += 8)
    tile[i][threadIdx.x] = W[(size_t)(r0 + i) * 3072 + 1024 + c0 + threadIdx.x];
  __syncthreads();
  for (int i = threadIdx.y; i < 32; i += 8) {
    float v = tile[threadIdx.x][i];
    unsigned short h, l; split2(v, h, l);
    size_t o = (size_t)(c0 + i) * 1024 + r0 + threadIdx.x;
    th[o] = h;
    tl[o] = l;
  }
}

// ------------- transpose + cast fp16 of E,F (4096x64) -> EFt (128 kk x 4096 n) -------------
__global__ void transpose_EF_f16(const float* __restrict__ E, const float* __restrict__ F,
                                 unsigned short* __restrict__ t) {
  __shared__ float tile[32][33];
  const float* src = blockIdx.z ? F : E;
  const int kkbase = blockIdx.z * 64;
  int c0 = blockIdx.x * 32, r0 = blockIdx.y * 32;   // c: k-col of E, r: n
  for (int i = threadIdx.y; i < 32; i += 8)
    tile[i][threadIdx.x] = src[(size_t)(r0 + i) * 64 + c0 + threadIdx.x];
  __syncthreads();
  for (int i = threadIdx.y; i < 32; i += 8)
    t[(size_t)(kkbase + c0 + i) * 4096 + r0 + threadIdx.x] = f2h(tile[threadIdx.x][i]);
}

// ------------- cast x (16M f32) -> fp16 (memory-bound, vectorized) -------------
__global__ __launch_bounds__(256) void cast_x_f16(
    const float* __restrict__ src, unsigned short* __restrict__ d) {
  const int total4 = DIMN * DIMB * 1024 / 4;   // 4,194,304 float4s
  int i = blockIdx.x * 256 + threadIdx.x;
  const int stride = gridDim.x * 256;
  for (; i < total4; i += stride) {
    float4 v = ((const float4*)src)[i];
    ushort4 h;
    h.x = f2h(v.x); h.y = f2h(v.y); h.z = f2h(v.z); h.w = f2h(v.w);
    ((ushort4*)d)[i] = h;
  }
}

// ------------- fp16 MFMA GEMM for q (DMA staging, BK=64, swizzled LDS) -------------
// q(16384x1024) = x @ Wq + bq ; scatter q (b,h,n,d) bf16. A=[m][k] fp16, Bt=[n][k] fp16.
__global__ __launch_bounds__(256) void gemm_q_f16(
    const unsigned short* __restrict__ A, const unsigned short* __restrict__ Bt,
    const float* __restrict__ bias, unsigned short* __restrict__ q)
{
  __shared__ unsigned short As[128 * 64];   // 16 KB
  __shared__ unsigned short Bs[128 * 64];   // 16 KB
  const int tid  = threadIdx.x;
  const int wave = tid >> 6, lane = tid & 63;
  const int quad = lane >> 4, l16 = lane & 15;
  const int wm = (wave >> 1) * 64, wn = (wave & 1) * 64;
  const int m0 = blockIdx.x * 128, n0 = blockIdx.y * 128;
  const unsigned short* Ab = A  + (size_t)m0 * 1024;
  const unsigned short* Bb = Bt + (size_t)n0 * 1024;

  f32x4 acc[4][4] = {};

  for (int k0 = 0; k0 < 1024; k0 += 64) {
    stage_tile64(Ab, 1024, As, tid, k0);
    stage_tile64(Bb, 1024, Bs, tid, k0);
    __syncthreads();   // drains vmcnt(0) -> DMA complete
    #pragma unroll
    for (int kh = 0; kh < 2; ++kh) {
      f16x8 af[4], bfr[4];
      #pragma unroll
      for (int i = 0; i < 4; ++i) af[i]  = ldh8(frag_ptr64(As, wm + 16 * i + l16, kh * 4 + quad));
      #pragma unroll
      for (int j = 0; j < 4; ++j) bfr[j] = ldh8(frag_ptr64(Bs, wn + 16 * j + l16, kh * 4 + quad));
      #pragma unroll
      for (int i = 0; i < 4; ++i)
        #pragma unroll
        for (int j = 0; j < 4; ++j)
          acc[i][j] = mfma16h(af[i], bfr[j], acc[i][j]);
    }
    __syncthreads();
  }

  #pragma unroll
  for (int i = 0; i < 4; ++i)
    #pragma unroll
    for (int j = 0; j < 4; ++j) {
      int col = n0 + wn + 16 * j + l16;     // 0..1023 (q cols)
      float bs = bias[col];
      int h = col >> 6, d = col & 63;
      #pragma unroll
      for (int r = 0; r < 4; ++r) {
        int row = m0 + wm + 16 * i + quad * 4 + r;
        int n = row >> 2, b = row & 3;      // x row-major (N,B,DIM): row = n*4+b
        q[(((size_t)(b * DIMH + h) * DIMN + n) << 6) + d] = f2bf(acc[i][j][r] + bs);
      }
    }
}

// ------------- split-K fp16 MFMA GEMM: partial[ks][kk128][c4096] = EFt[kk][n] . x[n][c] -------------
__global__ __launch_bounds__(256) void gemm_xEF(
    const unsigned short* __restrict__ xf, const unsigned short* __restrict__ ef,
    float* __restrict__ partial)
{
  __shared__ unsigned short Ash[128 * 40];
  __shared__ unsigned short Bsh[128 * 40];
  const int tid  = threadIdx.x;
  const int wave = tid >> 6, lane = tid & 63;
  const int quad = lane >> 4, l16 = lane & 15;
  const int wm = (wave >> 1) * 64, wn = (wave & 1) * 64;
  const int c0 = blockIdx.x * 128;
  const int ks = blockIdx.y;

  f32x4 acc[4][4] = {};

  const int kend = ks * 512 + 512;
  for (int k0 = ks * 512; k0 < kend; k0 += 32) {
    #pragma unroll
    for (int s = 0; s < 2; ++s) {
      int idx = tid + s * 256;
      int row = idx >> 2;             // kk 0..127
      int kc  = (idx & 3) * 8;        // n-local 0..31
      *(i32x4*)&Ash[row * 40 + kc] = *(const i32x4*)&ef[(size_t)row * 4096 + k0 + kc];
    }
    // B staging: LDS transpose-scatter x[n][c] -> Bs[c][n]
    #pragma unroll
    for (int s = 0; s < 2; ++s) {
      int n_l = tid & 31;
      int c8  = (tid >> 5) + s * 8;   // 0..15
      u16x8 vh = *(const u16x8*)&xf[(size_t)(k0 + n_l) * 4096 + c0 + c8 * 8];
      #pragma unroll
      for (int e = 0; e < 8; ++e)
        Bsh[(c8 * 8 + e) * 40 + n_l] = vh[e];
    }
    __syncthreads();
    f16x8 afh[4], bfh[4];
    #pragma unroll
    for (int i = 0; i < 4; ++i) afh[i] = ldh8(&Ash[(wm + 16 * i + l16) * 40 + quad * 8]);
    #pragma unroll
    for (int j = 0; j < 4; ++j) bfh[j] = ldh8(&Bsh[(wn + 16 * j + l16) * 40 + quad * 8]);
    #pragma unroll
    for (int i = 0; i < 4; ++i)
      #pragma unroll
      for (int j = 0; j < 4; ++j)
        acc[i][j] = mfma16h(afh[i], bfh[j], acc[i][j]);
    __syncthreads();
  }

  #pragma unroll
  for (int i = 0; i < 4; ++i)
    #pragma unroll
    for (int j = 0; j < 4; ++j) {
      int col = c0 + wn + 16 * j + l16;
      #pragma unroll
      for (int r = 0; r < 4; ++r) {
        int m = wm + 16 * i + quad * 4 + r;   // kk' 0..127
        partial[((size_t)ks * 128 + m) * 4096 + col] = acc[i][j][r];
      }
    }
}

// ------------- reduce split-K partials -> xEF bf16 hi/lo in [m][k] GEMM layout -------------
// m = t*256 + b*64 + (kk&63), k = c&1023  (t = kk>>6, b = c>>10)
__global__ __launch_bounds__(256) void reduce_xEF2(
    const float* __restrict__ partial, unsigned short* __restrict__ xh,
    unsigned short* __restrict__ xl)
{
  int t_lin = blockIdx.x * 256 + threadIdx.x;   // kk*4096 + c
  float s = 0.f;
  #pragma unroll
  for (int ks = 0; ks < 8; ++ks)
    s += partial[(size_t)ks * 524288 + t_lin];
  int kk = t_lin >> 12, c = t_lin & 4095;
  int t = kk >> 6, kkl = kk & 63, b = c >> 10, k = c & 1023;
  int m = t * 256 + b * 64 + kkl;
  unsigned short h, l; split2(s, h, l);
  xh[m * 1024 + k] = h;
  xl[m * 1024 + k] = l;
}

// ------------- column sums of E,F stage 1: partS[src][chunk16][kk64] -------------
__global__ __launch_bounds__(256) void colsum_EF1(
    const float* __restrict__ E, const float* __restrict__ F,
    float* __restrict__ partS)
{
  const int src = blockIdx.x;          // 0..1
  const int ch  = blockIdx.y;          // 0..15
  const float* S = src ? F : E;
  const int r  = threadIdx.x >> 6;     // 0..3
  const int kk = threadIdx.x & 63;
  const int n0 = ch * 256;
  float s = 0.f;
  #pragma unroll 8
  for (int i = 0; i < 64; ++i)
    s += S[(size_t)(n0 + r + 4 * i) * 64 + kk];
  __shared__ float red[4][64];
  red[r][kk] = s;
  __syncthreads();
  if (r == 0)
    partS[((size_t)src * 16 + ch) * 64 + kk] = red[0][kk] + red[1][kk] + red[2][kk] + red[3][kk];
}

// ------------- column sums stage 2: sEF[src*64+kk] = sum_ch partS -------------
__global__ void colsum_EF2(const float* __restrict__ partS, float* __restrict__ sEF) {
  int t = threadIdx.x;                 // 0..127
  int src = t >> 6, kk = t & 63;
  float s = 0.f;
  #pragma unroll
  for (int ch = 0; ch < 16; ++ch)
    s += partS[((size_t)src * 16 + ch) * 64 + kk];
  sEF[t] = s;
}

// ------------- klow/vlow via 3-product bf16 MFMA GEMM (M=512, N=1024, K=1024) -------------
// A = xEF hi/lo [m][k] (m = t*256+b*64+kk); B = WkvT hi/lo [t*1024+c][k].
// global_load_lds staging + swizzled LDS. Epilogue adds sEF[kk]*bias, scatters fp32.
__global__ __launch_bounds__(256) void gemm_klv(
    const unsigned short* __restrict__ Ah, const unsigned short* __restrict__ Al,
    const unsigned short* __restrict__ Bh, const unsigned short* __restrict__ Bl,
    const float* __restrict__ bias, const float* __restrict__ sEF,
    float* __restrict__ klow, float* __restrict__ vlow)
{
  __shared__ unsigned short Ash[128 * 32], Asl[128 * 32];
  __shared__ unsigned short Bsh[128 * 32], Bsl[128 * 32];
  const int tid  = threadIdx.x;
  const int wave = tid >> 6, lane = tid & 63;
  const int quad = lane >> 4, l16 = lane & 15;
  const int wm = (wave >> 1) * 64, wn = (wave & 1) * 64;
  const int mt = blockIdx.y;           // 0..3
  const int t  = mt >> 1;
  const int m0 = mt * 128;
  const int n0 = blockIdx.x * 128;     // c-tile within t
  const int brow = t * 1024 + n0;
  const unsigned short* Ahb = Ah + (size_t)m0 * 1024;
  const unsigned short* Alb = Al + (size_t)m0 * 1024;
  const unsigned short* Bhb = Bh + (size_t)brow * 1024;
  const unsigned short* Blb = Bl + (size_t)brow * 1024;

  f32x4 acc[4][4] = {};

  for (int k0 = 0; k0 < 1024; k0 += 32) {
    stage_tile(Ahb, 1024, Ash, tid, k0);
    stage_tile(Alb, 1024, Asl, tid, k0);
    stage_tile(Bhb, 1024, Bsh, tid, k0);
    stage_tile(Blb, 1024, Bsl, tid, k0);
    __syncthreads();
    bf16x8 afh[4], afl[4], bfh[4], bfl[4];
    #pragma unroll
    for (int i = 0; i < 4; ++i) {
      afh[i] = ldbf8(frag_ptr(Ash, wm + 16 * i + l16, quad));
      afl[i] = ldbf8(frag_ptr(Asl, wm + 16 * i + l16, quad));
    }
    #pragma unroll
    for (int j = 0; j < 4; ++j) {
      bfh[j] = ldbf8(frag_ptr(Bsh, wn + 16 * j + l16, quad));
      bfl[j] = ldbf8(frag_ptr(Bsl, wn + 16 * j + l16, quad));
    }
    #pragma unroll
    for (int i = 0; i < 4; ++i)
      #pragma unroll
      for (int j = 0; j < 4; ++j) {
        acc[i][j] = mfma16(afh[i], bfh[j], acc[i][j]);
        acc[i][j] = mfma16(afh[i], bfl[j], acc[i][j]);
        acc[i][j] = mfma16(afl[i], bfh[j], acc[i][j]);
      }
    __syncthreads();
  }

  float* dstb = (t ? vlow : klow);
  #pragma unroll
  for (int i = 0; i < 4; ++i)
    #pragma unroll
    for (int j = 0; j < 4; ++j) {
      int c = n0 + wn + 16 * j + l16;       // 0..1023
      int h = c >> 6, d = c & 63;
      float bs = bias[1024 * (1 + t) + c];
      #pragma unroll
      for (int r = 0; r < 4; ++r) {
        int m = m0 + wm + 16 * i + quad * 4 + r;
        int b = (m >> 6) & 3, kk = m & 63;
        float val = acc[i][j][r] + sEF[t * 64 + kk] * bs;
        dstb[(((size_t)b * DIMH + h) * DIMK + kk) * DH + d] = val;
      }
    }
}

// ------------- fused dots -> softmax -> PV -------------
// KL/VL fp32; K and V split hi/lo bf16 for MFMA (near-fp32 logits & PV).
__global__ __launch_bounds__(256) void attn_fused(
    const unsigned short* __restrict__ qb, const float* __restrict__ klow,
    const float* __restrict__ vlow, unsigned short* __restrict__ ctx)
{
  __shared__ unsigned short VTh[64][72], VTl[64][72];  // [d][k], k<72
  __shared__ unsigned short Plds[4][32][72];
  const int bh = blockIdx.x, b = bh >> 4, h = bh & 15;
  const unsigned short* Q  = qb   + (size_t)bh * DIMN * DH;
  const float* KL = klow + (size_t)bh * DIMK * DH;
  const float* VL = vlow + (size_t)bh * DIMK * DH;
  const int tid = threadIdx.x, wave = tid >> 6, lane = tid & 63;
  const int quad = lane >> 4, l16 = lane & 15;

  #pragma unroll
  for (int it = 0; it < 2; ++it) {
    int idx = tid + it * 256;
    int kk = idx >> 3, d0 = (idx & 7) * 8;
    float4 f0 = *(const float4*)&VL[kk * DH + d0];
    float4 f1 = *(const float4*)&VL[kk * DH + d0 + 4];
    float vv[8] = {f0.x, f0.y, f0.z, f0.w, f1.x, f1.y, f1.z, f1.w};
    #pragma unroll
    for (int e = 0; e < 8; ++e) {
      unsigned short hh, ll;
      split2(vv[e], hh, ll);
      VTh[d0 + e][kk] = hh;
      VTl[d0 + e][kk] = ll;
    }
  }
  bf16x8 kfh[2][4], kfl[2][4];
  #pragma unroll
  for (int dc = 0; dc < 2; ++dc)
    #pragma unroll
    for (int j = 0; j < 4; ++j) {
      const float* p = &KL[(j * 16 + l16) * DH + dc * 32 + quad * 8];
      float4 f0 = *(const float4*)p;
      float4 f1 = *(const float4*)(p + 4);
      float vv[8] = {f0.x, f0.y, f0.z, f0.w, f1.x, f1.y, f1.z, f1.w};
      alignas(16) unsigned short th[8], tl[8];
      #pragma unroll
      for (int e = 0; e < 8; ++e) split2(vv[e], th[e], tl[e]);
      kfh[dc][j] = ldbf8(th);
      kfl[dc][j] = ldbf8(tl);
    }
  __syncthreads();

  const int n_base = blockIdx.y * 128 + wave * 32;

  f32x4 sacc[2][4] = {};
  #pragma unroll
  for (int rt = 0; rt < 2; ++rt)
    #pragma unroll
    for (int dc = 0; dc < 2; ++dc) {
      bf16x8 a = ldbf8(&Q[(size_t)(n_base + rt * 16 + l16) * DH + dc * 32 + quad * 8]);
      #pragma unroll
      for (int j = 0; j < 4; ++j) {
        sacc[rt][j] = mfma16(a, kfh[dc][j], sacc[rt][j]);
        sacc[rt][j] = mfma16(a, kfl[dc][j], sacc[rt][j]);
      }
    }

  const float scale = 0.125f;
  #pragma unroll
  for (int rt = 0; rt < 2; ++rt)
    #pragma unroll
    for (int r = 0; r < 4; ++r) {
      float v0 = sacc[rt][0][r] * scale, v1 = sacc[rt][1][r] * scale;
      float v2 = sacc[rt][2][r] * scale, v3 = sacc[rt][3][r] * scale;
      float mx = fmaxf(fmaxf(v0, v1), fmaxf(v2, v3));
      #pragma unroll
      for (int off = 1; off < 16; off <<= 1)
        mx = fmaxf(mx, __shfl_xor(mx, off, 64));
      float e0 = __expf(v0 - mx), e1 = __expf(v1 - mx);
      float e2 = __expf(v2 - mx), e3 = __expf(v3 - mx);
      float sm = e0 + e1 + e2 + e3;
      #pragma unroll
      for (int off = 1; off < 16; off <<= 1)
        sm += __shfl_xor(sm, off, 64);
      float inv = 1.0f / sm;
      int prow = rt * 16 + quad * 4 + r;
      Plds[wave][prow][ 0 + l16] = f2bf(e0 * inv);
      Plds[wave][prow][16 + l16] = f2bf(e1 * inv);
      Plds[wave][prow][32 + l16] = f2bf(e2 * inv);
      Plds[wave][prow][48 + l16] = f2bf(e3 * inv);
    }
  __syncthreads();

  f32x4 oacc[2][4] = {};
  #pragma unroll
  for (int rt = 0; rt < 2; ++rt)
    #pragma unroll
    for (int kc = 0; kc < 2; ++kc) {
      bf16x8 a = ldbf8(&Plds[wave][rt * 16 + l16][kc * 32 + quad * 8]);
      #pragma unroll
      for (int j = 0; j < 4; ++j) {
        bf16x8 bh_ = ldbf8(&VTh[j * 16 + l16][kc * 32 + quad * 8]);
        bf16x8 bl_ = ldbf8(&VTl[j * 16 + l16][kc * 32 + quad * 8]);
        oacc[rt][j] = mfma16(a, bh_, oacc[rt][j]);
        oacc[rt][j] = mfma16(a, bl_, oacc[rt][j]);
      }
    }

  #pragma unroll
  for (int rt = 0; rt < 2; ++rt)
    #pragma unroll
    for (int j = 0; j < 4; ++j)
      #pragma unroll
      for (int r = 0; r < 4; ++r) {
        int n = n_base + rt * 16 + quad * 4 + r;
        ctx[((size_t)(n * DIMB + b) << 10) + h * DH + j * 16 + l16] = f2bf(oacc[rt][j][r]);
      }
}

// ---------------- 128x128 bf16 MFMA GEMM (final projection, DMA BK=64 staging) ----------------
__global__ __launch_bounds__(256) void gemm128_out(
    const unsigned short* __restrict__ A, const unsigned short* __restrict__ Bt,
    const float* __restrict__ bias, float* __restrict__ outF)
{
  __shared__ unsigned short As[128 * 64];   // 16 KB
  __shared__ unsigned short Bs[128 * 64];   // 16 KB
  const int tid  = threadIdx.x;
  const int wave = tid >> 6, lane = tid & 63;
  const int quad = lane >> 4, l16 = lane & 15;
  const int wm = (wave >> 1) * 64, wn = (wave & 1) * 64;
  const int m0 = blockIdx.x * 128, n0 = blockIdx.y * 128;
  const unsigned short* Ab = A  + (size_t)m0 * 1024;
  const unsigned short* Bb = Bt + (size_t)n0 * 1024;

  f32x4 acc[4][4] = {};

  for (int k0 = 0; k0 < 1024; k0 += 64) {
    stage_tile64(Ab, 1024, As, tid, k0);
    stage_tile64(Bb, 1024, Bs, tid, k0);
    __syncthreads();
    #pragma unroll
    for (int kh = 0; kh < 2; ++kh) {
      bf16x8 af[4], bfr[4];
      #pragma unroll
      for (int i = 0; i < 4; ++i) af[i]  = ldbf8(frag_ptr64(As, wm + 16 * i + l16, kh * 4 + quad));
      #pragma unroll
      for (int j = 0; j < 4; ++j) bfr[j] = ldbf8(frag_ptr64(Bs, wn + 16 * j + l16, kh * 4 + quad));
      #pragma unroll
      for (int i = 0; i < 4; ++i)
        #pragma unroll
        for (int j = 0; j < 4; ++j)
          acc[i][j] = mfma16(af[i], bfr[j], acc[i][j]);
    }
    __syncthreads();
  }

  #pragma unroll
  for (int i = 0; i < 4; ++i)
    #pragma unroll
    for (int j = 0; j < 4; ++j) {
      int col = n0 + wn + 16 * j + l16;
      float bs = bias[col];
      #pragma unroll
      for (int r = 0; r < 4; ++r) {
        int row = m0 + wm + 16 * i + quad * 4 + r;
        outF[(size_t)row * 1024 + col] = acc[i][j][r] + bs;
      }
    }
}

// ---------------- launch ----------------
extern "C" void kernel_launch(void* const* d_in, const int* in_sizes, int n_in,
                              void* d_out, int out_size, void* d_ws, size_t ws_size,
                              hipStream_t stream) {
  const float* x    = (const float*)d_in[0];
  const float* E    = (const float*)d_in[1];
  const float* F    = (const float*)d_in[2];
  const float* Wqkv = (const float*)d_in[3];
  const float* bqkv = (const float*)d_in[4];
  const float* Wout = (const float*)d_in[5];
  const float* bout = (const float*)d_in[6];
  float* out = (float*)d_out;

  const size_t MB = 1024 * 1024;
  char* ws = (char*)d_ws;
  // ---- workspace: ~81.4 MB (<100 MB proven bound), phase-aliased ----
  unsigned short* qb    = (unsigned short*)ws;                  // [0,32) MB (phase B+C)
  float*          partQ = (float*)ws;                           // [0,16) MB (phase A, dead before qb)
  unsigned short* xf16  = (unsigned short*)(ws + 32 * MB);      // [32,64) MB (phase A+B)
  unsigned short* ctx   = (unsigned short*)(ws + 32 * MB);      // [32,64) alias after xf16 dies
  unsigned short* wqT   = (unsigned short*)(ws + 64 * MB);      // 2 MB
  unsigned short* WoutT = (unsigned short*)(ws + 66 * MB);      // 2 MB
  unsigned short* eft   = (unsigned short*)(ws + 68 * MB);      // 1 MB
  unsigned short* xEFh  = (unsigned short*)(ws + 69 * MB);      // 1 MB  [m512][k1024] bf16 hi
  unsigned short* xEFl  = (unsigned short*)(ws + 70 * MB);      // 1 MB  bf16 lo
  unsigned short* wkvh  = (unsigned short*)(ws + 71 * MB);      // 4 MB  [n2048][k1024] bf16 hi
  unsigned short* wkvl  = (unsigned short*)(ws + 75 * MB);      // 4 MB  bf16 lo
  float*          sEF   = (float*)(ws + 79 * MB);               // 512 B
  float*          klow  = (float*)(ws + 79 * MB + 65536);       // 1 MB
  float*          vlow  = (float*)(ws + 80 * MB + 65536);       // 1 MB
  float*          partS = (float*)(ws + 81 * MB + 65536);       // 8 KB (colsum partials)

  // phase A: fp16 casts; E^T x / F^T x as split-K fp16 MFMA GEMM (partials in dead qb region);
  //          K/V projection as 3-product bf16 MFMA GEMM.
  transpose_wq_f16<<<dim3(32, 32), dim3(32, 8), 0, stream>>>(Wqkv, wqT);
  cast_x_f16<<<dim3(2048), dim3(256), 0, stream>>>(x, xf16);
  transpose_EF_f16<<<dim3(2, 128, 2), dim3(32, 8), 0, stream>>>(E, F, eft);
  transpose_split_wkv<<<dim3(64, 32), dim3(32, 8), 0, stream>>>(Wqkv, wkvh, wkvl);
  gemm_xEF<<<dim3(32, 8), dim3(256), 0, stream>>>(xf16, eft, partQ);
  reduce_xEF2<<<dim3(2048), dim3(256), 0, stream>>>(partQ, xEFh, xEFl);
  colsum_EF1<<<dim3(2, 16), dim3(256), 0, stream>>>(E, F, partS);
  colsum_EF2<<<dim3(1), dim3(128), 0, stream>>>(partS, sEF);
  gemm_klv<<<dim3(8, 4), dim3(256), 0, stream>>>(xEFh, xEFl, wkvh, wkvl, bqkv, sEF, klow, vlow);

  // phase B: q GEMM (overwrites partQ region with qb; xf16 dies after)
  gemm_q_f16<<<dim3(128, 8), dim3(256), 0, stream>>>(xf16, wqT, bqkv, qb);

  // phase C: attention + output projection (ctx over dead xf16)
  transpose_cast<<<dim3(32, 32), dim3(32, 8), 0, stream>>>(Wout, WoutT, 1024, 1024);
  attn_fused<<<dim3(64, 32), dim3(256), 0, stream>>>(qb, klow, vlow, ctx);
  gemm128_out<<<dim3(128, 8), dim3(256), 0, stream>>>(ctx, WoutT, bout, out);
}